// Round 1
// baseline (247.958 us; speedup 1.0000x reference)
//
#include <hip/hip_runtime.h>
#include <stdint.h>

// FlowNetC correlation, bf16 MFMA banded-GEMM, v5.
// out[b, iy*21+ix, h, w] = (1/256) sum_c in1[b,c,h,w] * in2[b,c,h+dy,w+dx]
// Parity split w=2u+r, w'=2v+r, v=u+ix-10 -> banded Gram per (b, h-pair, r).
// ws layout (both inputs): [inp][b][h][row=r*48+u][c 256] bf16, 49152 B/row.
//
// v5 change vs v4.1: A has ZERO intra-block reuse, so LDS staging of A was
// pure latency coupling (1 wg/CU, per-iter vmcnt(0) drain of a 50KB DMA,
// ~5160 cyc/iter vs ~800 of work). Now:
//  - block = (b, h2, u0-tile), 2 waves (parity). grid 1536, b = gid&7 so all
//    blocks of one batch land on one XCD (L2 working set 52MB -> ~6MB).
//  - A fragments: direct global->VGPR, double-buffered (prefetch dist 1).
//  - B fragments: direct global->VGPR once; edge u0 blocks skip the all-zero
//    band tiles (7 real 16x16 tiles per (b,h2,i) instead of 9).
//  - LDS only holds the per-block output tile sO[2][21][35] (stride 35 ==
//    3 mod 32 -> <=4-way scatter conflicts vs 8-way before). Out-of-band sO
//    cells are i-invariant: zeroed once, never rewritten.
//  - 4 blocks/CU (regs ~190 < 256, LDS 11.8KB) -> latency hiding across
//    blocks instead of a single barrier-convoyed workgroup.

#define CP    256            // c row (512 B, 64B-aligned segments for A loads)
#define WSROW (96 * CP)      // 24576 bf16 = 49152 B per (input,b,h)

typedef __bf16 bf16x8 __attribute__((ext_vector_type(8)));
typedef float  f32x4  __attribute__((ext_vector_type(4)));

// ---------------- Phase 1: pack fp32 -> bf16, direct (no LDS)
// grid 1024 = [inp(2)][b(8)][h(64)], block 384 = cig(4) x x(96)
__global__ __launch_bounds__(384) void pack_kernel(
    const float* __restrict__ in1, const float* __restrict__ in2,
    __bf16* __restrict__ ws) {
  const int id = blockIdx.x;
  const float* src = (id >> 9) ? in2 : in1;
  const int bh = id & 511;
  const int b = bh >> 6, h = bh & 63;
  const int t = threadIdx.x;
  const int x = t % 96, cig = t / 96;           // cig in [0,4)
  const int row = (x & 1) * 48 + (x >> 1);      // parity-major row index

  const size_t sbase = (size_t)b * (256 * 64 * 96) + (size_t)h * 96 + x;
  __bf16* dst = ws + (size_t)id * WSROW + (size_t)row * CP;

#pragma unroll
  for (int g = 0; g < 8; ++g) {                 // c-chunks of 32
    const int cb = g * 32 + cig * 8;
    float v[8];
#pragma unroll
    for (int k = 0; k < 8; ++k)
      v[k] = src[sbase + (size_t)(cb + k) * (64 * 96)];
    bf16x8 o;
#pragma unroll
    for (int k = 0; k < 8; ++k) o[k] = (__bf16)v[k];
    *(bf16x8*)(dst + cb) = o;
  }
}

// ---------------- Phase 2: MFMA band-GEMM, block = (b, h2, u0-tile), 2 waves
__global__ __launch_bounds__(128, 2) void corr_mfma(
    const __bf16* __restrict__ ws, float* __restrict__ out) {
  const int gid = blockIdx.x;          // 1536 = [u0i(3)][h2(64)][b(8)]
  const int b = gid & 7;               // XCD affinity: blockIdx % 8 -> XCD
  const int rest = gid >> 3;
  const int h2 = rest & 63;
  const int u0i = rest >> 6;           // 0..2
  const int u0 = u0i << 4;
  const int t = threadIdx.x;
  const int rr = t >> 6;               // wave = parity
  const int lane = t & 63;
  const int col = lane & 15, quad = lane >> 4;
  const float scale = 1.0f / 256.0f;

  const __bf16* ws1 = ws;
  const __bf16* ws2 = ws + (size_t)512 * WSROW;

  __shared__ float sO[2][21][35];      // stride 35: scatter <=4-way, mostly 2-way

  // Zero both sO buffers once. Valid-band cells are overwritten every iter;
  // out-of-band cells (v = u0+du+ix-10 outside [0,48)) are i-invariant zeros.
  for (int idx = t; idx < 2 * 21 * 35; idx += 128) ((float*)sO)[idx] = 0.0f;
  __syncthreads();                     // init visible before first scatter

  // Zero-fill out rows (output h-row = h2) whose in2 source row is invalid;
  // this block covers w-slice [2u0, 2u0+32).
  {
    const float4 z4 = {0.f, 0.f, 0.f, 0.f};
    for (int i = 0; i < 21; ++i) {
      int hh = h2 + 2 * i - 20;
      if (hh < 0 || hh >= 64) {
        float* obase = out + ((size_t)(b * 441 + i * 21) * 64 + h2) * 96 + 2 * u0;
        for (int idx = t; idx < 168; idx += 128) {
          int ix = idx >> 3, g = idx & 7;
          *(float4*)(obase + (size_t)ix * 6144 + 4 * g) = z4;
        }
      }
    }
  }

  // Band tiles this u0 needs (edge blocks drop their all-zero tile).
  const int tl = (u0i == 0) ? 1 : 0;
  const int th = (u0i == 2) ? 1 : 2;

  // B fragments -> registers (once). All v in the tl..th range are in-image.
  bf16x8 bfrag[3][8];
  {
    const __bf16* brow = ws2 + (size_t)(b * 64 + h2) * WSROW;
#pragma unroll
    for (int tt = 0; tt < 3; ++tt) {
      if (tt < tl || tt > th) continue;          // uniform branch
      const int v = u0 + 16 * (tt - 1) + col;
      const __bf16* p = brow + (size_t)(rr * 48 + v) * CP + quad * 8;
#pragma unroll
      for (int s = 0; s < 8; ++s)
        bfrag[tt][s] = *(const bf16x8*)(p + 32 * s);
    }
  }

  // Valid dy range: h = h2 - 2i + 20 in [0, 64)
  const int i_lo = max(0, (h2 - 42) >> 1);
  const int i_hi = min(20, (h2 + 20) >> 1);

  const int aoff = (rr * 48 + u0 + col) * CP + quad * 8;   // per-lane, i-invariant

  auto loadA = [&](bf16x8(&a)[8], int i) {
    const __bf16* p = ws1 + (size_t)(b * 64 + (h2 - 2 * i + 20)) * WSROW + aoff;
#pragma unroll
    for (int s = 0; s < 8; ++s) a[s] = *(const bf16x8*)(p + 32 * s);
  };

  auto body = [&](const bf16x8(&a)[8], int i, int ob) {
    f32x4 acc[3];
#pragma unroll
    for (int tt = 0; tt < 3; ++tt) acc[tt] = (f32x4){0.f, 0.f, 0.f, 0.f};
#pragma unroll
    for (int tt = 0; tt < 3; ++tt) {
      if (tt < tl || tt > th) continue;
#pragma unroll
      for (int s = 0; s < 8; ++s)
        acc[tt] = __builtin_amdgcn_mfma_f32_16x16x32_bf16(a[s], bfrag[tt][s],
                                                          acc[tt], 0, 0, 0);
    }
    // Scatter C into sO[ob]: D row = u-off = quad*4+reg, D col = v-off = col
#pragma unroll
    for (int tt = 0; tt < 3; ++tt) {
      if (tt < tl || tt > th) continue;
#pragma unroll
      for (int reg = 0; reg < 4; ++reg) {
        int du = quad * 4 + reg;
        int ix = (tt - 1) * 16 + col - du + 10;
        if (ix >= 0 && ix < 21)
          sO[ob][ix][2 * du + rr] = acc[tt][reg] * scale;
      }
    }
    __syncthreads();                   // scatter done; epilogue may read sO[ob]
    const int h = h2 - 2 * i + 20;
    float* obase = out + ((size_t)(b * 441 + i * 21) * 64 + h) * 96 + 2 * u0;
    for (int idx = t; idx < 168; idx += 128) {
      int ixx = idx >> 3, g = idx & 7;
      float4 v;
      v.x = sO[ob][ixx][4 * g + 0];
      v.y = sO[ob][ixx][4 * g + 1];
      v.z = sO[ob][ixx][4 * g + 2];
      v.w = sO[ob][ixx][4 * g + 3];
      *(float4*)(obase + (size_t)ixx * 6144 + 4 * g) = v;
    }
  };

  // Software-pipelined main loop: prefetch A(i+1) while computing i.
  bf16x8 a0[8], a1[8];
  int i = i_lo, ob = 0;
  loadA(a0, i);
  while (i + 1 <= i_hi) {
    loadA(a1, i + 1);
    body(a0, i, ob); ob ^= 1;
    if (i + 2 <= i_hi) loadA(a0, i + 2);
    body(a1, i + 1, ob); ob ^= 1;
    i += 2;
  }
  if (i <= i_hi) body(a0, i, ob);
}

extern "C" void kernel_launch(void* const* d_in, const int* in_sizes, int n_in,
                              void* d_out, int out_size, void* d_ws, size_t ws_size,
                              hipStream_t stream) {
  const float* in1 = (const float*)d_in[0];
  const float* in2 = (const float*)d_in[1];
  float* out = (float*)d_out;
  __bf16* ws = (__bf16*)d_ws;    // 1024 * 24576 bf16 = 50.3 MB

  pack_kernel<<<1024, 384, 0, stream>>>(in1, in2, ws);
  corr_mfma<<<1536, 128, 0, stream>>>(ws, out);
}

// Round 2
// 238.895 us; speedup vs baseline: 1.0379x; 1.0379x over previous
//
#include <hip/hip_runtime.h>
#include <stdint.h>

// FlowNetC correlation, bf16 MFMA banded-GEMM, v6.
// out[b, iy*21+ix, h, w] = (1/256) sum_c in1[b,c,h,w] * in2[b,c,h+dy,w+dx]
// Parity split w=2u+r, w'=2v+r, v=u+ix-10 -> banded Gram per (b, h-pair, r).
// ws layout (both inputs): [inp][b][h][row=r*48+u][c 256] bf16. in1 is
// pre-scaled by 1/256 during pack (exact: power of 2).
//
// v6 vs v5 (v5 was latency-bound: per-iter __syncthreads drains vmcnt(0),
// killing the A-prefetch every iteration -> ~4200 cyc/iter observed):
//  - Hot-loop barrier is now raw s_barrier + explicit lgkmcnt(0) only
//    (T4 counted-vmcnt pattern): A prefetch loads stay in flight across the
//    barrier; compiler emits counted vmcnt for their first use.
//  - Band range split in two i-halves per block -> grid 3072, and h2 is
//    remapped middle-out so long (21-band) blocks dispatch first.
//  - pack: thread remap (x=t>>2, cig=t&3) -> each wave's stores form 16 FULL
//    64B lines instead of touching 64 partial lines (4x fewer write txns).
//  - scale folded into pack.

#define CP    256            // c row (512 B)
#define WSROW (96 * CP)      // 24576 bf16 = 49152 B per (input,b,h)

typedef __bf16 bf16x8 __attribute__((ext_vector_type(8)));
typedef float  f32x4  __attribute__((ext_vector_type(4)));

// ---------------- Phase 1: pack fp32 -> bf16, direct (no LDS)
// grid 1024 = [inp(2)][b(8)][h(64)], block 384 = x(96) x cig(4)
__global__ __launch_bounds__(384) void pack_kernel(
    const float* __restrict__ in1, const float* __restrict__ in2,
    __bf16* __restrict__ ws) {
  const int id = blockIdx.x;
  const float* src = (id >> 9) ? in2 : in1;
  const float scale = (id >> 9) ? 1.0f : 0.00390625f;   // in1 *= 1/256 (exact)
  const int bh = id & 511;
  const int b = bh >> 6, h = bh & 63;
  const int t = threadIdx.x;
  const int x = t >> 2, cig = t & 3;            // 4 lanes share one x
  const int row = (x & 1) * 48 + (x >> 1);      // parity-major row index

  const size_t sbase = (size_t)b * (256 * 64 * 96) + (size_t)h * 96 + x;
  __bf16* dst = ws + (size_t)id * WSROW + (size_t)row * CP;

#pragma unroll
  for (int g = 0; g < 8; ++g) {                 // c-chunks of 32
    const int cb = g * 32 + cig * 8;
    float v[8];
#pragma unroll
    for (int k = 0; k < 8; ++k)
      v[k] = src[sbase + (size_t)(cb + k) * (64 * 96)];
    bf16x8 o;
#pragma unroll
    for (int k = 0; k < 8; ++k) o[k] = (__bf16)(v[k] * scale);
    *(bf16x8*)(dst + cb) = o;                   // 4 lanes -> one full 64B line
  }
}

// ---------------- Phase 2: MFMA band-GEMM
// grid 3072 = [half(2)*u0i(3)][j(64)][b(8)], block 128 = 2 waves (parity)
__global__ __launch_bounds__(128, 2) void corr_mfma(
    const __bf16* __restrict__ ws, float* __restrict__ out) {
  const int gid = blockIdx.x;
  const int b = gid & 7;               // XCD affinity
  const int rest = gid >> 3;
  const int j = rest & 63;
  // middle-out h2 order: long-band blocks (h2 ~ 32) dispatch first
  const int h2 = (j & 1) ? (31 - (j >> 1)) : (32 + (j >> 1));
  const int rest2 = rest >> 6;         // 0..5
  const int u0i = rest2 % 3;
  const int half = rest2 / 3;
  const int u0 = u0i << 4;
  const int t = threadIdx.x;
  const int rr = t >> 6;               // wave = parity
  const int lane = t & 63;
  const int col = lane & 15, quad = lane >> 4;

  const __bf16* ws1 = ws;
  const __bf16* ws2 = ws + (size_t)512 * WSROW;

  __shared__ float sO[2][21][35];      // stride 35: scatter mostly-2-way

  // Zero both sO buffers once; out-of-band cells are i-invariant zeros.
  for (int idx = t; idx < 2 * 21 * 35; idx += 128) ((float*)sO)[idx] = 0.0f;

  const int is0 = half * 11;           // this block's i-subrange [is0, ie0]
  const int ie0 = min(20, is0 + 10);

  // Zero-fill out rows (output h-row = h2) whose in2 source row is invalid.
  {
    const float4 z4 = {0.f, 0.f, 0.f, 0.f};
    for (int i = is0; i <= ie0; ++i) {
      int hh = h2 + 2 * i - 20;
      if (hh < 0 || hh >= 64) {
        float* obase = out + ((size_t)(b * 441 + i * 21) * 64 + h2) * 96 + 2 * u0;
        for (int idx = t; idx < 168; idx += 128) {
          int ix = idx >> 3, g = idx & 7;
          *(float4*)(obase + (size_t)ix * 6144 + 4 * g) = z4;
        }
      }
    }
  }

  // Valid compute range for this sub-block
  const int i_lo = max(max(0, (h2 - 42) >> 1), is0);
  const int i_hi = min(min(20, (h2 + 20) >> 1), ie0);
  if (i_lo > i_hi) return;             // block-uniform

  __syncthreads();                     // sO init visible before first scatter

  // Band tiles this u0 needs (edge blocks drop their all-zero tile).
  const int tl = (u0i == 0) ? 1 : 0;
  const int th = (u0i == 2) ? 1 : 2;

  // B fragments -> registers (once). All v in the tl..th range are in-image.
  bf16x8 bfrag[3][8];
  {
    const __bf16* brow = ws2 + (size_t)(b * 64 + h2) * WSROW;
#pragma unroll
    for (int tt = 0; tt < 3; ++tt) {
      if (tt < tl || tt > th) continue;          // uniform branch
      const int v = u0 + 16 * (tt - 1) + col;
      const __bf16* p = brow + (size_t)(rr * 48 + v) * CP + quad * 8;
#pragma unroll
      for (int s = 0; s < 8; ++s)
        bfrag[tt][s] = *(const bf16x8*)(p + 32 * s);
    }
  }

  const int aoff = (rr * 48 + u0 + col) * CP + quad * 8;   // i-invariant

  auto loadA = [&](bf16x8(&a)[8], int i) {
    const __bf16* p = ws1 + (size_t)(b * 64 + (h2 - 2 * i + 20)) * WSROW + aoff;
#pragma unroll
    for (int s = 0; s < 8; ++s) a[s] = *(const bf16x8*)(p + 32 * s);
  };

  auto body = [&](const bf16x8(&a)[8], int i, int ob) {
    f32x4 acc[3];
#pragma unroll
    for (int tt = 0; tt < 3; ++tt) acc[tt] = (f32x4){0.f, 0.f, 0.f, 0.f};
#pragma unroll
    for (int tt = 0; tt < 3; ++tt) {
      if (tt < tl || tt > th) continue;
#pragma unroll
      for (int s = 0; s < 8; ++s)
        acc[tt] = __builtin_amdgcn_mfma_f32_16x16x32_bf16(a[s], bfrag[tt][s],
                                                          acc[tt], 0, 0, 0);
    }
    // Scatter C into sO[ob]: D row = u-off = quad*4+reg, D col = v-off = col
#pragma unroll
    for (int tt = 0; tt < 3; ++tt) {
      if (tt < tl || tt > th) continue;
#pragma unroll
      for (int reg = 0; reg < 4; ++reg) {
        int du = quad * 4 + reg;
        int ix = (tt - 1) * 16 + col - du + 10;
        if (ix >= 0 && ix < 21)
          sO[ob][ix][2 * du + rr] = acc[tt][reg];
      }
    }
    // Raw barrier: drain LDS only. Global A-prefetch stays in flight (T4).
    asm volatile("s_waitcnt lgkmcnt(0)" ::: "memory");
    __builtin_amdgcn_sched_barrier(0);
    __builtin_amdgcn_s_barrier();
    __builtin_amdgcn_sched_barrier(0);
    // Coalesced store of the [21][32] tile slice
    const int h = h2 - 2 * i + 20;
    float* obase = out + ((size_t)(b * 441 + i * 21) * 64 + h) * 96 + 2 * u0;
    for (int idx = t; idx < 168; idx += 128) {
      int ixx = idx >> 3, g = idx & 7;
      float4 v;
      v.x = sO[ob][ixx][4 * g + 0];
      v.y = sO[ob][ixx][4 * g + 1];
      v.z = sO[ob][ixx][4 * g + 2];
      v.w = sO[ob][ixx][4 * g + 3];
      *(float4*)(obase + (size_t)ixx * 6144 + 4 * g) = v;
    }
  };

  // Software-pipelined main loop: prefetch A(i+1) while computing i.
  bf16x8 a0[8], a1[8];
  int i = i_lo, ob = 0;
  loadA(a0, i);
  while (i + 1 <= i_hi) {
    loadA(a1, i + 1);
    body(a0, i, ob); ob ^= 1;
    if (i + 2 <= i_hi) loadA(a0, i + 2);
    body(a1, i + 1, ob); ob ^= 1;
    i += 2;
  }
  if (i <= i_hi) body(a0, i, ob);
}

extern "C" void kernel_launch(void* const* d_in, const int* in_sizes, int n_in,
                              void* d_out, int out_size, void* d_ws, size_t ws_size,
                              hipStream_t stream) {
  const float* in1 = (const float*)d_in[0];
  const float* in2 = (const float*)d_in[1];
  float* out = (float*)d_out;
  __bf16* ws = (__bf16*)d_ws;    // 1024 * 24576 bf16 = 50.3 MB

  pack_kernel<<<1024, 384, 0, stream>>>(in1, in2, ws);
  corr_mfma<<<3072, 128, 0, stream>>>(ws, out);
}

// Round 4
// 224.469 us; speedup vs baseline: 1.1046x; 1.0643x over previous
//
#include <hip/hip_runtime.h>
#include <stdint.h>

// FlowNetC correlation, bf16 MFMA banded-GEMM, v7.1 (compile fix of v7:
// __builtin_nontemporal_store needs a native vector type, not HIP float4).
// out[b, iy*21+ix, h, w] = (1/256) sum_c in1[b,c,h,w] * in2[b,c,h+dy,w+dx]
// Parity split w=2u+r, w'=2v+r, v=u+ix-10 -> banded Gram per (b, h-pair, r).
// ws layout (both inputs): [inp][b][h][row=r*48+u][c 256] bf16; in1 pre-scaled
// by 1/256 in pack (exact).
//
// v7 vs v6: v5/v6 were capped at ~2 waves/SIMD by per-wave register state
// (bfrag 96 + A dbuf 64 + acc ~ 200 regs on the unified file) -> ~5 waves/CU
// resident, nothing to hide per-iter L2 latency. Now block = 4 waves =
// (parity rr) x (channel-half kh): each wave handles K=128 -> bfrag 48,
// A dbuf 32, ~115 regs -> __launch_bounds__(256,4): 16 waves/CU (3x).
// Partial sums combined through sO[buf][kh] (no extra barriers).
// Also: sched_barrier(0) pins A-prefetch issue before the MFMAs; nontemporal
// output stores keep the streaming 7.5MB/b output from thrashing the 4MB
// XCD-L2 that caches ws[b]; grid 1536, natural h2 order.

#define CP    256            // c row (512 B)
#define WSROW (96 * CP)      // 24576 bf16 = 49152 B per (input,b,h)

typedef __bf16 bf16x8 __attribute__((ext_vector_type(8)));
typedef float  f32x4  __attribute__((ext_vector_type(4)));

// ---------------- Phase 1: pack fp32 -> bf16, direct (no LDS)
// grid 1024 = [inp(2)][b(8)][h(64)], block 384 = x(96) x cig(4)
__global__ __launch_bounds__(384) void pack_kernel(
    const float* __restrict__ in1, const float* __restrict__ in2,
    __bf16* __restrict__ ws) {
  const int id = blockIdx.x;
  const float* src = (id >> 9) ? in2 : in1;
  const float scale = (id >> 9) ? 1.0f : 0.00390625f;   // in1 *= 1/256 (exact)
  const int bh = id & 511;
  const int b = bh >> 6, h = bh & 63;
  const int t = threadIdx.x;
  const int x = t >> 2, cig = t & 3;            // 4 lanes share one x
  const int row = (x & 1) * 48 + (x >> 1);      // parity-major row index

  const size_t sbase = (size_t)b * (256 * 64 * 96) + (size_t)h * 96 + x;
  __bf16* dst = ws + (size_t)id * WSROW + (size_t)row * CP;

#pragma unroll
  for (int g = 0; g < 8; ++g) {                 // c-chunks of 32
    const int cb = g * 32 + cig * 8;
    float v[8];
#pragma unroll
    for (int k = 0; k < 8; ++k)
      v[k] = src[sbase + (size_t)(cb + k) * (64 * 96)];
    bf16x8 o;
#pragma unroll
    for (int k = 0; k < 8; ++k) o[k] = (__bf16)(v[k] * scale);
    *(bf16x8*)(dst + cb) = o;                   // 4 lanes -> one full 64B line
  }
}

// ---------------- Phase 2: MFMA band-GEMM
// grid 1536 = [u0i(3)][h2(64)][b(8)], block 256 = 4 waves = (rr x kh)
__global__ __launch_bounds__(256, 4) void corr_mfma(
    const __bf16* __restrict__ ws, float* __restrict__ out) {
  const int gid = blockIdx.x;
  const int b = gid & 7;               // XCD affinity
  const int rest = gid >> 3;
  const int h2 = rest & 63;
  const int u0i = rest >> 6;           // 0..2
  const int u0 = u0i << 4;
  const int t = threadIdx.x;
  const int wv = t >> 6;
  const int rr = wv & 1;               // parity
  const int kh = wv >> 1;              // channel half: c in [128*kh, 128*kh+128)
  const int lane = t & 63;
  const int col = lane & 15, quad = lane >> 4;

  const __bf16* ws1 = ws;
  const __bf16* ws2 = ws + (size_t)512 * WSROW;

  __shared__ float sO[2][2][21][35];   // [buf][khalf][ix][w-local], stride 35

  // Zero both buffers once; out-of-band cells are i-invariant zeros.
  for (int idx = t; idx < 2 * 2 * 21 * 35; idx += 256) ((float*)sO)[idx] = 0.0f;

  // Zero-fill out rows whose in2 source row h2+dy is out of image.
  {
    const f32x4 z4 = {0.f, 0.f, 0.f, 0.f};
    for (int i = 0; i < 21; ++i) {
      int hh = h2 + 2 * i - 20;
      if (hh < 0 || hh >= 64) {
        float* obase = out + ((size_t)(b * 441 + i * 21) * 64 + h2) * 96 + 2 * u0;
        for (int idx = t; idx < 168; idx += 256) {
          int ix = idx >> 3, g = idx & 7;
          __builtin_nontemporal_store(
              z4, (f32x4*)(obase + (size_t)ix * 6144 + 4 * g));
        }
      }
    }
  }

  const int i_lo = max(0, (h2 - 42) >> 1);
  const int i_hi = min(20, (h2 + 20) >> 1);

  __syncthreads();                     // sO init visible before first scatter

  // Band tiles this u0 needs (edge blocks drop their all-zero tile).
  const int tl = (u0i == 0) ? 1 : 0;
  const int th = (u0i == 2) ? 1 : 2;

  // B fragments -> registers (once), this wave's K-half only.
  bf16x8 bfrag[3][4];
  {
    const __bf16* brow = ws2 + (size_t)(b * 64 + h2) * WSROW;
#pragma unroll
    for (int tt = 0; tt < 3; ++tt) {
      if (tt < tl || tt > th) continue;          // uniform branch
      const int v = u0 + 16 * (tt - 1) + col;
      const __bf16* p = brow + (size_t)(rr * 48 + v) * CP + kh * 128 + quad * 8;
#pragma unroll
      for (int sl = 0; sl < 4; ++sl)
        bfrag[tt][sl] = *(const bf16x8*)(p + 32 * sl);
    }
  }

  const int aoff = (rr * 48 + u0 + col) * CP + kh * 128 + quad * 8;

  auto loadA = [&](bf16x8(&a)[4], int i) {
    const __bf16* p = ws1 + (size_t)(b * 64 + (h2 - 2 * i + 20)) * WSROW + aoff;
#pragma unroll
    for (int sl = 0; sl < 4; ++sl) a[sl] = *(const bf16x8*)(p + 32 * sl);
  };

  auto body = [&](const bf16x8(&a)[4], int i, int ob) {
    f32x4 acc[3];
#pragma unroll
    for (int tt = 0; tt < 3; ++tt) acc[tt] = (f32x4){0.f, 0.f, 0.f, 0.f};
#pragma unroll
    for (int tt = 0; tt < 3; ++tt) {
      if (tt < tl || tt > th) continue;
#pragma unroll
      for (int sl = 0; sl < 4; ++sl)
        acc[tt] = __builtin_amdgcn_mfma_f32_16x16x32_bf16(a[sl], bfrag[tt][sl],
                                                          acc[tt], 0, 0, 0);
    }
    // Scatter C into sO[ob][kh]: D row = u-off = quad*4+reg, D col = v-off
#pragma unroll
    for (int tt = 0; tt < 3; ++tt) {
      if (tt < tl || tt > th) continue;
#pragma unroll
      for (int reg = 0; reg < 4; ++reg) {
        int du = quad * 4 + reg;
        int ix = (tt - 1) * 16 + col - du + 10;
        if (ix >= 0 && ix < 21)
          sO[ob][kh][ix][2 * du + rr] = acc[tt][reg];
      }
    }
    // Raw barrier: drain LDS only; A-prefetch stays in flight (counted vmcnt).
    asm volatile("s_waitcnt lgkmcnt(0)" ::: "memory");
    __builtin_amdgcn_sched_barrier(0);
    __builtin_amdgcn_s_barrier();
    __builtin_amdgcn_sched_barrier(0);
    // Combine K-halves and store the [21][32] tile slice (nontemporal).
    const int h = h2 - 2 * i + 20;
    float* obase = out + ((size_t)(b * 441 + i * 21) * 64 + h) * 96 + 2 * u0;
    for (int idx = t; idx < 168; idx += 256) {
      int ixx = idx >> 3, g = idx & 7;
      f32x4 v;
      v.x = sO[ob][0][ixx][4 * g + 0] + sO[ob][1][ixx][4 * g + 0];
      v.y = sO[ob][0][ixx][4 * g + 1] + sO[ob][1][ixx][4 * g + 1];
      v.z = sO[ob][0][ixx][4 * g + 2] + sO[ob][1][ixx][4 * g + 2];
      v.w = sO[ob][0][ixx][4 * g + 3] + sO[ob][1][ixx][4 * g + 3];
      __builtin_nontemporal_store(
          v, (f32x4*)(obase + (size_t)ixx * 6144 + 4 * g));
    }
  };

  // Software-pipelined main loop: prefetch A(i+1) while computing i.
  // sched_barrier(0) after each loadA pins the load issue point (no sinking).
  bf16x8 a0[4], a1[4];
  int i = i_lo, ob = 0;
  loadA(a0, i);
  __builtin_amdgcn_sched_barrier(0);
  while (i + 1 <= i_hi) {
    loadA(a1, i + 1);
    __builtin_amdgcn_sched_barrier(0);
    body(a0, i, ob); ob ^= 1;
    if (i + 2 <= i_hi) {
      loadA(a0, i + 2);
      __builtin_amdgcn_sched_barrier(0);
    }
    body(a1, i + 1, ob); ob ^= 1;
    i += 2;
  }
  if (i <= i_hi) body(a0, i, ob);
}

extern "C" void kernel_launch(void* const* d_in, const int* in_sizes, int n_in,
                              void* d_out, int out_size, void* d_ws, size_t ws_size,
                              hipStream_t stream) {
  const float* in1 = (const float*)d_in[0];
  const float* in2 = (const float*)d_in[1];
  float* out = (float*)d_out;
  __bf16* ws = (__bf16*)d_ws;    // 1024 * 24576 bf16 = 50.3 MB

  pack_kernel<<<1024, 384, 0, stream>>>(in1, in2, ws);
  corr_mfma<<<1536, 256, 0, stream>>>(ws, out);
}